// Round 5
// baseline (200.352 us; speedup 1.0000x reference)
//
#include <hip/hip_runtime.h>
#include <hip/hip_bf16.h>
#include <math.h>

// Problem constants (FunctionNPairLoss): N=8192 rows, K=128 dims, 64 classes.
#define KD 128
#define NCLS 64
#define JSPLIT 8

typedef __attribute__((ext_vector_type(8))) short short8;
typedef __attribute__((ext_vector_type(4))) float f32x4;

__device__ inline void gload_lds16(const void* g, void* l) {
    __builtin_amdgcn_global_load_lds((const __attribute__((address_space(1))) unsigned int*)g,
                                     (__attribute__((address_space(3))) unsigned int*)l,
                                     16, 0, 0);
}

// ---------------- fused cvt+prep: bf16 convert, sq = ||row||^2, label counts ----------------
__global__ __launch_bounds__(256) void cvtprep_kernel(const float* __restrict__ emb,
                                                      const int* __restrict__ lab,
                                                      short* __restrict__ embb,
                                                      float* __restrict__ sq,
                                                      int* __restrict__ cnt, int N) {
    int w = (blockIdx.x * 256 + threadIdx.x) >> 6;
    int l = threadIdx.x & 63;
    int r0 = w * 4;
    if (r0 >= N) return;
    float2 v[4];
#pragma unroll
    for (int r = 0; r < 4; ++r)
        v[r] = *(const float2*)&emb[(size_t)(r0 + r) * KD + l * 2];
    float s[4];
#pragma unroll
    for (int r = 0; r < 4; ++r) {
        s[r] = v[r].x * v[r].x + v[r].y * v[r].y;
        __hip_bfloat16 h0 = __float2bfloat16(v[r].x);
        __hip_bfloat16 h1 = __float2bfloat16(v[r].y);
        unsigned int pk = ((unsigned int)*(unsigned short*)&h1 << 16) | (unsigned int)*(unsigned short*)&h0;
        *(unsigned int*)&embb[(size_t)(r0 + r) * KD + l * 2] = pk;
    }
#pragma unroll
    for (int r = 0; r < 4; ++r)
        for (int m = 32; m; m >>= 1) s[r] += __shfl_xor(s[r], m, 64);
    if (l == 0) {
#pragma unroll
        for (int r = 0; r < 4; ++r) {
            sq[r0 + r] = s[r];
            atomicAdd(&cnt[lab[r0 + r]], 1);
        }
    }
}

// ---------------- fused scan+scatter: one block, LDS cursors ----------------
__global__ __launch_bounds__(1024) void scan_scatter_kernel(const int* __restrict__ lab,
                                                            const int* __restrict__ cnt,
                                                            int* __restrict__ off,
                                                            int* __restrict__ list, int N) {
    __shared__ int offL[NCLS];
    __shared__ int curL[NCLS];
    int tid = threadIdx.x;
    if (tid < 64) {
        int v = cnt[tid];
        int s = v;
        for (int m = 1; m < 64; m <<= 1) {
            int t = __shfl_up(s, m, 64);
            if (tid >= m) s += t;
        }
        offL[tid] = s - v;
        curL[tid] = 0;
        off[tid] = s - v;
    }
    __syncthreads();
    for (int i = tid; i < N; i += 1024) {
        int c = lab[i];
        int p = atomicAdd(&curL[c], 1);
        list[offL[c] + p] = i;
    }
}

// ---------------- main fused kernel: grid (8+3, 64) ----------------
// blockIdx.x < 8:  zmfma path — Zall[i] = sum_{ALL j} exp(sq_i+sq_j-2*dot), unmasked,
//                  A-frags direct from global, B tiles double-buffered via global_load_lds.
// blockIdx.x >= 8: zsub path — same-label Gram chunk (qi,qj), exp(D) row/col sums ->
//                  global atomicAdd zsub[] (bitwise-identical MFMA => exact cancellation).
__global__ __launch_bounds__(256, 2) void zmain_kernel(const short* __restrict__ embb,
                                                       const float* __restrict__ sq,
                                                       const int* __restrict__ cnt,
                                                       const int* __restrict__ off,
                                                       const int* __restrict__ list,
                                                       float* __restrict__ Z,
                                                       float* __restrict__ zsub, int N) {
    __shared__ short8 B0[128 * 16];  // 32 KB
    __shared__ short8 B1[128 * 16];  // 32 KB
    __shared__ float sA[128], sB[128];
    __shared__ int gA[128], gB[128];

    const int tid = threadIdx.x;
    const int w = tid >> 6, l = tid & 63;
    const int wr = w >> 1, wc = w & 1;
    const short8* embv = (const short8*)embb;
    const int bx = blockIdx.x;

    if (bx < JSPLIT) {
        // ================= zmfma path =================
        const int i0 = blockIdx.y * 128;
        const int jBeg = bx * (N / JSPLIT);

        // A fragments direct from global (L2-hot, no swizzle needed)
        short8 af[4][4];
#pragma unroll
        for (int mi = 0; mi < 4; ++mi) {
            int row = i0 + wr * 64 + mi * 16 + (l & 15);
#pragma unroll
            for (int ks = 0; ks < 4; ++ks)
                af[mi][ks] = embv[(size_t)row * 16 + ks * 4 + (l >> 4)];
        }
        // stage first B tile; swizzled source: LDS[row][c] = G[row][c^(row&7)]
#pragma unroll
        for (int it = 0; it < 8; ++it) {
            int lr = w * 32 + it * 4 + (l >> 4);
            int c = (l & 15) ^ (lr & 7);
            gload_lds16(embv + (size_t)(jBeg + lr) * 16 + c, &B0[w * 512 + it * 64]);
        }

        float sqi[4][4];
#pragma unroll
        for (int mi = 0; mi < 4; ++mi)
#pragma unroll
            for (int r = 0; r < 4; ++r)
                sqi[mi][r] = sq[i0 + wr * 64 + mi * 16 + (l >> 4) * 4 + r];
        float zsum[4][4];
#pragma unroll
        for (int mi = 0; mi < 4; ++mi)
#pragma unroll
            for (int r = 0; r < 4; ++r) zsum[mi][r] = 0.f;

        __syncthreads();  // B0 staged (drains vmcnt, also covers af loads)

        const int nj = N / JSPLIT / 128;
        for (int jt = 0; jt < nj; ++jt) {
            short8* rb = (jt & 1) ? B1 : B0;
            short8* sb = (jt & 1) ? B0 : B1;
            if (jt + 1 < nj) {
                int j1 = jBeg + (jt + 1) * 128;
#pragma unroll
                for (int it = 0; it < 8; ++it) {
                    int lr = w * 32 + it * 4 + (l >> 4);
                    int c = (l & 15) ^ (lr & 7);
                    gload_lds16(embv + (size_t)(j1 + lr) * 16 + c, &sb[w * 512 + it * 64]);
                }
            }

            f32x4 acc[4][4];
#pragma unroll
            for (int mi = 0; mi < 4; ++mi)
#pragma unroll
                for (int ni = 0; ni < 4; ++ni) acc[mi][ni] = (f32x4){0.f, 0.f, 0.f, 0.f};

#pragma unroll
            for (int ks = 0; ks < 4; ++ks) {
                short8 bf[4];
                int kc = ks * 4 + (l >> 4);
#pragma unroll
                for (int ni = 0; ni < 4; ++ni) {
                    int row = wc * 64 + ni * 16 + (l & 15);
                    bf[ni] = rb[row * 16 + (kc ^ (row & 7))];
                }
#pragma unroll
                for (int mi = 0; mi < 4; ++mi)
#pragma unroll
                    for (int ni = 0; ni < 4; ++ni)
                        acc[mi][ni] = __builtin_amdgcn_mfma_f32_16x16x32_bf16(af[mi][ks], bf[ni], acc[mi][ni], 0, 0, 0);
            }

            int j0 = jBeg + jt * 128;
            float sqj[4];
#pragma unroll
            for (int ni = 0; ni < 4; ++ni)
                sqj[ni] = sq[j0 + wc * 64 + ni * 16 + (l & 15)];
#pragma unroll
            for (int mi = 0; mi < 4; ++mi)
#pragma unroll
                for (int ni = 0; ni < 4; ++ni)
#pragma unroll
                    for (int r = 0; r < 4; ++r) {
                        float D = fmaf(-2.f, acc[mi][ni][r], sqi[mi][r] + sqj[ni]);
                        zsum[mi][r] += __expf(D);
                    }
            __syncthreads();  // staged sb landed; all waves done with rb
        }

#pragma unroll
        for (int mi = 0; mi < 4; ++mi)
#pragma unroll
            for (int r = 0; r < 4; ++r) {
                float v = zsum[mi][r];
                v += __shfl_xor(v, 1, 64);
                v += __shfl_xor(v, 2, 64);
                v += __shfl_xor(v, 4, 64);
                v += __shfl_xor(v, 8, 64);
                if ((l & 15) == 0)
                    atomicAdd(&Z[i0 + wr * 64 + mi * 16 + (l >> 4) * 4 + r], v);
            }
    } else {
        // ================= zsub path =================
        const int qq = bx - JSPLIT;
        const int qi = (qq == 2) ? 1 : 0;
        const int qj = (qq == 0) ? 0 : 1;
        const int c = blockIdx.y;
        const int k = cnt[c], base = off[c];
        if (k < 2 || qi * 128 >= k || qj * 128 >= k) return;

        if (tid < 128) {
            int g = list[base + min(qi * 128 + tid, k - 1)];
            gA[tid] = g; sA[tid] = sq[g];
        } else {
            int t2 = tid - 128;
            int g = list[base + min(qj * 128 + t2, k - 1)];
            gB[t2] = g; sB[t2] = sq[g];
        }
        __syncthreads();

        // fragments gathered directly from global (tiny volume, L2-hot)
        short8 af[4][4];
#pragma unroll
        for (int mi = 0; mi < 4; ++mi) {
            int g = gA[wr * 64 + mi * 16 + (l & 15)];
#pragma unroll
            for (int ks = 0; ks < 4; ++ks)
                af[mi][ks] = embv[(size_t)g * 16 + ks * 4 + (l >> 4)];
        }
        f32x4 acc[4][4];
#pragma unroll
        for (int mi = 0; mi < 4; ++mi)
#pragma unroll
            for (int ni = 0; ni < 4; ++ni) acc[mi][ni] = (f32x4){0.f, 0.f, 0.f, 0.f};
#pragma unroll
        for (int ks = 0; ks < 4; ++ks) {
            short8 bfk[4];
            int kc = ks * 4 + (l >> 4);
#pragma unroll
            for (int ni = 0; ni < 4; ++ni)
                bfk[ni] = embv[(size_t)gB[wc * 64 + ni * 16 + (l & 15)] * 16 + kc];
#pragma unroll
            for (int mi = 0; mi < 4; ++mi)
#pragma unroll
                for (int ni = 0; ni < 4; ++ni)
                    acc[mi][ni] = __builtin_amdgcn_mfma_f32_16x16x32_bf16(af[mi][ks], bfk[ni], acc[mi][ni], 0, 0, 0);
        }

        // e = exp(D) masked; row sums (+ col sums if off-diagonal chunk)
        float rowsum[4][4];
#pragma unroll
        for (int mi = 0; mi < 4; ++mi)
#pragma unroll
            for (int r = 0; r < 4; ++r) rowsum[mi][r] = 0.f;
        float colsum[4] = {0.f, 0.f, 0.f, 0.f};
#pragma unroll
        for (int mi = 0; mi < 4; ++mi)
#pragma unroll
            for (int ni = 0; ni < 4; ++ni) {
                int pL = wr * 64 + mi * 16 + (l >> 4) * 4;
                int qL = wc * 64 + ni * 16 + (l & 15);
                int p = qi * 128 + pL, q = qj * 128 + qL;
#pragma unroll
                for (int r = 0; r < 4; ++r) {
                    float D = fmaf(-2.f, acc[mi][ni][r], sA[pL + r] + sB[qL]);
                    float e = ((p + r) < k && q < k) ? __expf(D) : 0.f;
                    rowsum[mi][r] += e;
                    colsum[ni] += e;
                }
            }
#pragma unroll
        for (int mi = 0; mi < 4; ++mi)
#pragma unroll
            for (int r = 0; r < 4; ++r) {
                float v = rowsum[mi][r];
                v += __shfl_xor(v, 1, 64);
                v += __shfl_xor(v, 2, 64);
                v += __shfl_xor(v, 4, 64);
                v += __shfl_xor(v, 8, 64);
                if ((l & 15) == 0)
                    atomicAdd(&zsub[gA[wr * 64 + mi * 16 + (l >> 4) * 4 + r]], v);
            }
        if (qi != qj) {
#pragma unroll
            for (int ni = 0; ni < 4; ++ni) {
                float v = colsum[ni];
                v += __shfl_xor(v, 16, 64);
                v += __shfl_xor(v, 32, 64);
                if ((l >> 4) == 0)
                    atomicAdd(&zsub[gB[wc * 64 + ni * 16 + (l & 15)]], v);
            }
        }
    }
}

// ---------------- loss pass: grid (3, 64), direct-gathered Gram, Zf = Zall - zsub ----------------
__global__ __launch_bounds__(256, 2) void loss_kernel(const short* __restrict__ embb,
                                                      const float* __restrict__ sq,
                                                      const float* __restrict__ Z,
                                                      const float* __restrict__ zsub,
                                                      const int* __restrict__ cnt,
                                                      const int* __restrict__ off,
                                                      const int* __restrict__ list,
                                                      float* __restrict__ lsum) {
    __shared__ float sA[128], sB[128], zfA[128], zfB[128];
    __shared__ int gA[128], gB[128];
    __shared__ float red[4];

    const int qq = blockIdx.x;
    const int qi = (qq == 2) ? 1 : 0;
    const int qj = (qq == 0) ? 0 : 1;
    const int c = blockIdx.y;
    const int k = cnt[c], base = off[c];
    if (k < 2 || qi * 128 >= k || qj * 128 >= k) return;

    const int tid = threadIdx.x;
    const int w = tid >> 6, l = tid & 63;
    const int wr = w >> 1, wc = w & 1;
    const short8* embv = (const short8*)embb;

    if (tid < 128) {
        int g = list[base + min(qi * 128 + tid, k - 1)];
        gA[tid] = g; sA[tid] = sq[g]; zfA[tid] = Z[g] - zsub[g];
    } else {
        int t2 = tid - 128;
        int g = list[base + min(qj * 128 + t2, k - 1)];
        gB[t2] = g; sB[t2] = sq[g]; zfB[t2] = Z[g] - zsub[g];
    }
    __syncthreads();

    short8 af[4][4];
#pragma unroll
    for (int mi = 0; mi < 4; ++mi) {
        int g = gA[wr * 64 + mi * 16 + (l & 15)];
#pragma unroll
        for (int ks = 0; ks < 4; ++ks)
            af[mi][ks] = embv[(size_t)g * 16 + ks * 4 + (l >> 4)];
    }
    f32x4 acc[4][4];
#pragma unroll
    for (int mi = 0; mi < 4; ++mi)
#pragma unroll
        for (int ni = 0; ni < 4; ++ni) acc[mi][ni] = (f32x4){0.f, 0.f, 0.f, 0.f};
#pragma unroll
    for (int ks = 0; ks < 4; ++ks) {
        short8 bfk[4];
        int kc = ks * 4 + (l >> 4);
#pragma unroll
        for (int ni = 0; ni < 4; ++ni)
            bfk[ni] = embv[(size_t)gB[wc * 64 + ni * 16 + (l & 15)] * 16 + kc];
#pragma unroll
        for (int mi = 0; mi < 4; ++mi)
#pragma unroll
            for (int ni = 0; ni < 4; ++ni)
                acc[mi][ni] = __builtin_amdgcn_mfma_f32_16x16x32_bf16(af[mi][ks], bfk[ni], acc[mi][ni], 0, 0, 0);
    }

    float part = 0.f;
#pragma unroll
    for (int mi = 0; mi < 4; ++mi)
#pragma unroll
        for (int ni = 0; ni < 4; ++ni) {
            int qL = wc * 64 + ni * 16 + (l & 15);
            int q = qj * 128 + qL;
#pragma unroll
            for (int r = 0; r < 4; ++r) {
                int pL = wr * 64 + mi * 16 + (l >> 4) * 4 + r;
                int p = qi * 128 + pL;
                bool valid = (p < q) && (q < k);
                float D = fmaf(-2.f, acc[mi][ni][r], sA[pL] + sB[qL]);
                int a = gA[pL], b = gB[qL];
                float z = (a < b) ? zfA[pL] : zfB[qL];
                float x = valid ? z * __expf(-D) : 0.f;
                part += __logf(1.f + x);
            }
        }

    for (int m = 32; m; m >>= 1) part += __shfl_xor(part, m, 64);
    if (l == 0) red[w] = part;
    __syncthreads();
    if (tid == 0)
        atomicAdd(&lsum[c], red[0] + red[1] + red[2] + red[3]);
}

// ---------------- finalize ----------------
__global__ void fin_kernel(const float* __restrict__ lsum, const int* __restrict__ cnt,
                           float* __restrict__ out) {
    int c = threadIdx.x;
    float mean = 0.f;
    int valid = 0;
    if (c < NCLS) {
        long k = cnt[c];
        long np = k * (k - 1) / 2;
        if (np > 0) { mean = lsum[c] / (float)np; valid = 1; }
    }
    float sm = mean;
    int sv = valid;
    for (int m = 32; m; m >>= 1) {
        sm += __shfl_xor(sm, m, 64);
        sv += __shfl_xor(sv, m, 64);
    }
    if (c == 0) out[0] = sm / (float)max(sv, 1);
}

extern "C" void kernel_launch(void* const* d_in, const int* in_sizes, int n_in,
                              void* d_out, int out_size, void* d_ws, size_t ws_size,
                              hipStream_t stream) {
    const float* emb = (const float*)d_in[0];
    const int* lab = (const int*)d_in[1];
    float* out = (float*)d_out;
    const int N = in_sizes[1];  // 8192

    // workspace (4B units): [Z | zsub | lsum | cnt] zeroed in one memset
    float* ws = (float*)d_ws;
    float* Z = ws;                          // N (Zall)
    float* zsub = ws + N;                   // N
    float* lsum = ws + 2 * N;               // 64
    int* cnt = (int*)(ws + 2 * N + NCLS);   // 64
    int* off = cnt + NCLS;                  // 64
    int* list = off + NCLS;                 // N
    float* sq = (float*)(list + N);         // N
    short* embb = (short*)(sq + N);         // N*KD bf16 (2 MB), 16B-aligned

    hipMemsetAsync(Z, 0, (size_t)(2 * N + 2 * NCLS) * 4, stream);
    cvtprep_kernel<<<N / 16, 256, 0, stream>>>(emb, lab, embb, sq, cnt, N);
    scan_scatter_kernel<<<1, 1024, 0, stream>>>(lab, cnt, off, list, N);
    dim3 zgrid(JSPLIT + 3, N / 128);
    zmain_kernel<<<zgrid, 256, 0, stream>>>(embb, sq, cnt, off, list, Z, zsub, N);
    dim3 lgrid(3, NCLS);
    loss_kernel<<<lgrid, 256, 0, stream>>>(embb, sq, Z, zsub, cnt, off, list, lsum);
    fin_kernel<<<1, 64, 0, stream>>>(lsum, cnt, out);
}

// Round 6
// 153.616 us; speedup vs baseline: 1.3042x; 1.3042x over previous
//
#include <hip/hip_runtime.h>
#include <hip/hip_bf16.h>
#include <math.h>

// Problem constants (FunctionNPairLoss): N=8192 rows, K=128 dims, 64 classes.
#define KD 128
#define NCLS 64
#define JSPLIT 8

typedef __attribute__((ext_vector_type(8))) short short8;
typedef __attribute__((ext_vector_type(4))) float f32x4;

__device__ inline void gload_lds16(const void* g, void* l) {
    __builtin_amdgcn_global_load_lds((const __attribute__((address_space(1))) unsigned int*)g,
                                     (__attribute__((address_space(3))) unsigned int*)l,
                                     16, 0, 0);
}

// ---------------- fused cvt+prep: bf16 convert, sq = ||row||^2, label counts ----------------
// 4 rows/wave, loads issued up-front (runs inside the harness poison-fill HBM window)
__global__ __launch_bounds__(256) void cvtprep_kernel(const float* __restrict__ emb,
                                                      const int* __restrict__ lab,
                                                      short* __restrict__ embb,
                                                      float* __restrict__ sq,
                                                      int* __restrict__ cnt, int N) {
    int w = (blockIdx.x * 256 + threadIdx.x) >> 6;
    int l = threadIdx.x & 63;
    int r0 = w * 4;
    if (r0 >= N) return;
    float2 v[4];
#pragma unroll
    for (int r = 0; r < 4; ++r)
        v[r] = *(const float2*)&emb[(size_t)(r0 + r) * KD + l * 2];
    float s[4];
#pragma unroll
    for (int r = 0; r < 4; ++r) {
        s[r] = v[r].x * v[r].x + v[r].y * v[r].y;
        __hip_bfloat16 h0 = __float2bfloat16(v[r].x);
        __hip_bfloat16 h1 = __float2bfloat16(v[r].y);
        unsigned int pk = ((unsigned int)*(unsigned short*)&h1 << 16) | (unsigned int)*(unsigned short*)&h0;
        *(unsigned int*)&embb[(size_t)(r0 + r) * KD + l * 2] = pk;
    }
#pragma unroll
    for (int r = 0; r < 4; ++r)
        for (int m = 32; m; m >>= 1) s[r] += __shfl_xor(s[r], m, 64);
    if (l == 0) {
#pragma unroll
        for (int r = 0; r < 4; ++r) {
            sq[r0 + r] = s[r];
            atomicAdd(&cnt[lab[r0 + r]], 1);
        }
    }
}

// ---------------- fused scan+scatter: one block, LDS cursors ----------------
__global__ __launch_bounds__(1024) void scan_scatter_kernel(const int* __restrict__ lab,
                                                            const int* __restrict__ cnt,
                                                            int* __restrict__ off,
                                                            int* __restrict__ list, int N) {
    __shared__ int offL[NCLS];
    __shared__ int curL[NCLS];
    int tid = threadIdx.x;
    if (tid < 64) {
        int v = cnt[tid];
        int s = v;
        for (int m = 1; m < 64; m <<= 1) {
            int t = __shfl_up(s, m, 64);
            if (tid >= m) s += t;
        }
        offL[tid] = s - v;
        curL[tid] = 0;
        off[tid] = s - v;
    }
    __syncthreads();
    for (int i = tid; i < N; i += 1024) {
        int c = lab[i];
        int p = atomicAdd(&curL[c], 1);
        list[offL[c] + p] = i;
    }
}

// ---------------- MFMA Z pass (MASKED) — round-4 proven structure ----------------
// Z[i] = sum_{j: lab[j]!=lab[i]} exp(sq[i]+sq[j]-2*dot(e_i,e_j))
// 128x128 tile, 4 waves 2x2; A staged via swizzled global_load_lds, hoisted to regs,
// As8 then reused as second B double-buffer slot (2-phase: stage t+1 before compute t).
__global__ __launch_bounds__(256, 2) void zmfma_kernel(const short* __restrict__ embb,
                                                       const int* __restrict__ lab,
                                                       const float* __restrict__ sq,
                                                       float* __restrict__ Z, int N) {
    __shared__ short8 As8[128 * 16];  // 32 KB: A stage, then B dbuf slot 1
    __shared__ short8 Bs8[128 * 16];  // 32 KB: B dbuf slot 0

    const int tid = threadIdx.x;
    const int w = tid >> 6, l = tid & 63;
    const int wr = w >> 1, wc = w & 1;
    const int i0 = blockIdx.y * 128;
    const int jBeg = blockIdx.x * (N / JSPLIT);
    const short8* embv = (const short8*)embb;

    // stage A tile and first B tile; swizzled source: LDS[row][c] = G[row][c^(row&7)]
#pragma unroll
    for (int it = 0; it < 8; ++it) {
        int lr = w * 32 + it * 4 + (l >> 4);
        int c = (l & 15) ^ (lr & 7);
        gload_lds16(embv + (size_t)(i0 + lr) * 16 + c, &As8[w * 512 + it * 64]);
    }
#pragma unroll
    for (int it = 0; it < 8; ++it) {
        int lr = w * 32 + it * 4 + (l >> 4);
        int c = (l & 15) ^ (lr & 7);
        gload_lds16(embv + (size_t)(jBeg + lr) * 16 + c, &Bs8[w * 512 + it * 64]);
    }

    float sqi[4][4]; int labi[4][4];
#pragma unroll
    for (int mi = 0; mi < 4; ++mi)
#pragma unroll
        for (int r = 0; r < 4; ++r) {
            int i = i0 + wr * 64 + mi * 16 + (l >> 4) * 4 + r;
            sqi[mi][r] = sq[i];
            labi[mi][r] = lab[i];
        }
    float zsum[4][4];
#pragma unroll
    for (int mi = 0; mi < 4; ++mi)
#pragma unroll
        for (int r = 0; r < 4; ++r) zsum[mi][r] = 0.f;

    __syncthreads();  // A and B0 staged

    // hoist A fragments (loop-invariant over j)
    short8 af[4][4];
#pragma unroll
    for (int mi = 0; mi < 4; ++mi) {
        int row = wr * 64 + mi * 16 + (l & 15);
        int rs = row * 16, rx = row & 7;
#pragma unroll
        for (int ks = 0; ks < 4; ++ks) {
            int kc = ks * 4 + (l >> 4);
            af[mi][ks] = As8[rs + (kc ^ rx)];
        }
    }
    __syncthreads();  // all waves done reading As8 -> free for B buffering

    const int nj = N / JSPLIT / 128;
    for (int jt = 0; jt < nj; ++jt) {
        short8* rb = (jt & 1) ? As8 : Bs8;   // read tile jt
        short8* sb = (jt & 1) ? Bs8 : As8;   // stage tile jt+1
        if (jt + 1 < nj) {
            int j1 = jBeg + (jt + 1) * 128;
#pragma unroll
            for (int it = 0; it < 8; ++it) {
                int lr = w * 32 + it * 4 + (l >> 4);
                int c = (l & 15) ^ (lr & 7);
                gload_lds16(embv + (size_t)(j1 + lr) * 16 + c, &sb[w * 512 + it * 64]);
            }
        }

        f32x4 acc[4][4];
#pragma unroll
        for (int mi = 0; mi < 4; ++mi)
#pragma unroll
            for (int ni = 0; ni < 4; ++ni) acc[mi][ni] = (f32x4){0.f, 0.f, 0.f, 0.f};

#pragma unroll
        for (int ks = 0; ks < 4; ++ks) {
            short8 bf[4];
            int kc = ks * 4 + (l >> 4);
#pragma unroll
            for (int ni = 0; ni < 4; ++ni) {
                int row = wc * 64 + ni * 16 + (l & 15);
                bf[ni] = rb[row * 16 + (kc ^ (row & 7))];
            }
#pragma unroll
            for (int mi = 0; mi < 4; ++mi)
#pragma unroll
                for (int ni = 0; ni < 4; ++ni)
                    acc[mi][ni] = __builtin_amdgcn_mfma_f32_16x16x32_bf16(af[mi][ks], bf[ni], acc[mi][ni], 0, 0, 0);
        }

        // epilogue: D = sqi + sqj - 2*dot; label-masked exp; accumulate per-i
        int j0 = jBeg + jt * 128;
        float sqj[4]; int labj[4];
#pragma unroll
        for (int ni = 0; ni < 4; ++ni) {
            int j = j0 + wc * 64 + ni * 16 + (l & 15);
            sqj[ni] = sq[j];
            labj[ni] = lab[j];
        }
#pragma unroll
        for (int mi = 0; mi < 4; ++mi)
#pragma unroll
            for (int ni = 0; ni < 4; ++ni)
#pragma unroll
                for (int r = 0; r < 4; ++r) {
                    float D = fmaf(-2.f, acc[mi][ni][r], sqi[mi][r] + sqj[ni]);
                    float e = __expf(D);
                    zsum[mi][r] += (labj[ni] != labi[mi][r]) ? e : 0.f;
                }
        __syncthreads();  // staged sb landed; all waves done with rb
    }

    // reduce across the 16 lanes sharing each i, atomic into Z
#pragma unroll
    for (int mi = 0; mi < 4; ++mi)
#pragma unroll
        for (int r = 0; r < 4; ++r) {
            float v = zsum[mi][r];
            v += __shfl_xor(v, 1, 64);
            v += __shfl_xor(v, 2, 64);
            v += __shfl_xor(v, 4, 64);
            v += __shfl_xor(v, 8, 64);
            if ((l & 15) == 0)
                atomicAdd(&Z[i0 + wr * 64 + mi * 16 + (l >> 4) * 4 + r], v);
        }
}

// ---------------- loss pass: grid (3, 64), direct-gathered Gram ----------------
// quadrants (qi,qj) of the label's 256-row cap: 0=(0,0), 1=(0,1), 2=(1,1).
// loss += log(1 + Z[anchor]*exp(-D)) over list-position pairs p<q; anchor = min global id.
__global__ __launch_bounds__(256, 2) void loss_kernel(const short* __restrict__ embb,
                                                      const float* __restrict__ sq,
                                                      const float* __restrict__ Z,
                                                      const int* __restrict__ cnt,
                                                      const int* __restrict__ off,
                                                      const int* __restrict__ list,
                                                      float* __restrict__ lsum) {
    __shared__ float sA[128], sB[128], zfA[128], zfB[128];
    __shared__ int gA[128], gB[128];
    __shared__ float red[4];

    const int qq = blockIdx.x;
    const int qi = (qq == 2) ? 1 : 0;
    const int qj = (qq == 0) ? 0 : 1;
    const int c = blockIdx.y;
    const int k = cnt[c], base = off[c];
    if (k < 2 || qi * 128 >= k || qj * 128 >= k) return;

    const int tid = threadIdx.x;
    const int w = tid >> 6, l = tid & 63;
    const int wr = w >> 1, wc = w & 1;
    const short8* embv = (const short8*)embb;

    if (tid < 128) {
        int g = list[base + min(qi * 128 + tid, k - 1)];
        gA[tid] = g; sA[tid] = sq[g]; zfA[tid] = Z[g];
    } else {
        int t2 = tid - 128;
        int g = list[base + min(qj * 128 + t2, k - 1)];
        gB[t2] = g; sB[t2] = sq[g]; zfB[t2] = Z[g];
    }
    __syncthreads();

    short8 af[4][4];
#pragma unroll
    for (int mi = 0; mi < 4; ++mi) {
        int g = gA[wr * 64 + mi * 16 + (l & 15)];
#pragma unroll
        for (int ks = 0; ks < 4; ++ks)
            af[mi][ks] = embv[(size_t)g * 16 + ks * 4 + (l >> 4)];
    }
    f32x4 acc[4][4];
#pragma unroll
    for (int mi = 0; mi < 4; ++mi)
#pragma unroll
        for (int ni = 0; ni < 4; ++ni) acc[mi][ni] = (f32x4){0.f, 0.f, 0.f, 0.f};
#pragma unroll
    for (int ks = 0; ks < 4; ++ks) {
        short8 bfk[4];
        int kc = ks * 4 + (l >> 4);
#pragma unroll
        for (int ni = 0; ni < 4; ++ni)
            bfk[ni] = embv[(size_t)gB[wc * 64 + ni * 16 + (l & 15)] * 16 + kc];
#pragma unroll
        for (int mi = 0; mi < 4; ++mi)
#pragma unroll
            for (int ni = 0; ni < 4; ++ni)
                acc[mi][ni] = __builtin_amdgcn_mfma_f32_16x16x32_bf16(af[mi][ks], bfk[ni], acc[mi][ni], 0, 0, 0);
    }

    float part = 0.f;
#pragma unroll
    for (int mi = 0; mi < 4; ++mi)
#pragma unroll
        for (int ni = 0; ni < 4; ++ni) {
            int qL = wc * 64 + ni * 16 + (l & 15);
            int q = qj * 128 + qL;
#pragma unroll
            for (int r = 0; r < 4; ++r) {
                int pL = wr * 64 + mi * 16 + (l >> 4) * 4 + r;
                int p = qi * 128 + pL;
                bool valid = (p < q) && (q < k);
                float D = fmaf(-2.f, acc[mi][ni][r], sA[pL] + sB[qL]);
                int a = gA[pL], b = gB[qL];
                float z = (a < b) ? zfA[pL] : zfB[qL];
                float x = valid ? z * __expf(-D) : 0.f;
                part += __logf(1.f + x);
            }
        }

    for (int m = 32; m; m >>= 1) part += __shfl_xor(part, m, 64);
    if (l == 0) red[w] = part;
    __syncthreads();
    if (tid == 0)
        atomicAdd(&lsum[c], red[0] + red[1] + red[2] + red[3]);
}

// ---------------- finalize ----------------
__global__ void fin_kernel(const float* __restrict__ lsum, const int* __restrict__ cnt,
                           float* __restrict__ out) {
    int c = threadIdx.x;
    float mean = 0.f;
    int valid = 0;
    if (c < NCLS) {
        long k = cnt[c];
        long np = k * (k - 1) / 2;
        if (np > 0) { mean = lsum[c] / (float)np; valid = 1; }
    }
    float sm = mean;
    int sv = valid;
    for (int m = 32; m; m >>= 1) {
        sm += __shfl_xor(sm, m, 64);
        sv += __shfl_xor(sv, m, 64);
    }
    if (c == 0) out[0] = sm / (float)max(sv, 1);
}

extern "C" void kernel_launch(void* const* d_in, const int* in_sizes, int n_in,
                              void* d_out, int out_size, void* d_ws, size_t ws_size,
                              hipStream_t stream) {
    const float* emb = (const float*)d_in[0];
    const int* lab = (const int*)d_in[1];
    float* out = (float*)d_out;
    const int N = in_sizes[1];  // 8192

    // workspace (4B units): [Z | lsum | cnt] zeroed in one memset
    float* ws = (float*)d_ws;
    float* Z = ws;                          // N
    float* lsum = ws + N;                   // 64
    int* cnt = (int*)(ws + N + NCLS);       // 64
    int* off = cnt + NCLS;                  // 64
    int* list = off + NCLS;                 // N
    float* sq = (float*)(list + N);         // N
    short* embb = (short*)(sq + N);         // N*KD bf16 (2 MB), 16B-aligned

    hipMemsetAsync(Z, 0, (size_t)(N + 2 * NCLS) * 4, stream);
    cvtprep_kernel<<<N / 16, 256, 0, stream>>>(emb, lab, embb, sq, cnt, N);
    scan_scatter_kernel<<<1, 1024, 0, stream>>>(lab, cnt, off, list, N);
    dim3 zgrid(JSPLIT, N / 128);
    zmfma_kernel<<<zgrid, 256, 0, stream>>>(embb, lab, sq, Z, N);
    dim3 lgrid(3, NCLS);
    loss_kernel<<<lgrid, 256, 0, stream>>>(embb, sq, Z, cnt, off, list, lsum);
    fin_kernel<<<1, 64, 0, stream>>>(lsum, cnt, out);
}

// Round 7
// 113.321 us; speedup vs baseline: 1.7680x; 1.3556x over previous
//
#include <hip/hip_runtime.h>
#include <hip/hip_bf16.h>
#include <math.h>

// Problem constants (FunctionNPairLoss): N=8192 rows, K=128 dims, 64 classes.
#define KD 128
#define NCLS 64
#define LOG2E 1.4426950408889634f
#define NEG2L -2.8853900817779268f
#define POS2L 2.8853900817779268f

typedef __attribute__((ext_vector_type(8))) short short8;
typedef __attribute__((ext_vector_type(4))) float f32x4;

__device__ inline void gload_lds16(const void* g, void* l) {
    __builtin_amdgcn_global_load_lds((const __attribute__((address_space(1))) unsigned int*)g,
                                     (__attribute__((address_space(3))) unsigned int*)l,
                                     16, 0, 0);
}
// raw v_exp_f32 (2^x) / v_log_f32 (log2 x): single-instruction transcendentals
__device__ __forceinline__ float vexp2(float x) { float r; asm("v_exp_f32 %0, %1" : "=v"(r) : "v"(x)); return r; }
__device__ __forceinline__ float vlog2(float x) { float r; asm("v_log_f32 %0, %1" : "=v"(r) : "v"(x)); return r; }

// ---------------- cvt+prep: bf16 convert, s2 = ||row||^2 * log2e ----------------
// Runs inside the harness poison-fill writeback-drain window (~42us, memory-gated).
__global__ __launch_bounds__(256) void cvtprep_kernel(const float* __restrict__ emb,
                                                      short* __restrict__ embb,
                                                      float* __restrict__ s2, int N) {
    int w = (blockIdx.x * 256 + threadIdx.x) >> 6;
    int l = threadIdx.x & 63;
    int r0 = w * 4;
    if (r0 >= N) return;
    float2 v[4];
#pragma unroll
    for (int r = 0; r < 4; ++r)
        v[r] = *(const float2*)&emb[(size_t)(r0 + r) * KD + l * 2];
    float s[4];
#pragma unroll
    for (int r = 0; r < 4; ++r) {
        s[r] = v[r].x * v[r].x + v[r].y * v[r].y;
        __hip_bfloat16 h0 = __float2bfloat16(v[r].x);
        __hip_bfloat16 h1 = __float2bfloat16(v[r].y);
        unsigned int pk = ((unsigned int)*(unsigned short*)&h1 << 16) | (unsigned int)*(unsigned short*)&h0;
        *(unsigned int*)&embb[(size_t)(r0 + r) * KD + l * 2] = pk;
    }
#pragma unroll
    for (int r = 0; r < 4; ++r)
        for (int m = 32; m; m >>= 1) s[r] += __shfl_xor(s[r], m, 64);
    if (l == 0) {
#pragma unroll
        for (int r = 0; r < 4; ++r) s2[r0 + r] = s[r] * LOG2E;
    }
}

// ---------------- scan+scatter: self-counting, independent of cvtprep ----------------
__global__ __launch_bounds__(1024) void scan_scatter_kernel(const int* __restrict__ lab,
                                                            int* __restrict__ cnt,
                                                            int* __restrict__ off,
                                                            int* __restrict__ list, int N) {
    __shared__ int cntL[NCLS], offL[NCLS], curL[NCLS];
    int tid = threadIdx.x;
    if (tid < NCLS) cntL[tid] = 0;
    __syncthreads();
    for (int i = tid; i < N; i += 1024) atomicAdd(&cntL[lab[i]], 1);
    __syncthreads();
    if (tid < NCLS) {
        int v = cntL[tid];
        int s = v;
        for (int m = 1; m < 64; m <<= 1) {
            int t = __shfl_up(s, m, 64);
            if (tid >= m) s += t;
        }
        offL[tid] = s - v;
        curL[tid] = 0;
        off[tid] = s - v;
        cnt[tid] = v;
    }
    __syncthreads();
    for (int i = tid; i < N; i += 1024) {
        int c = lab[i];
        int p = atomicAdd(&curL[c], 1);
        list[offL[c] + p] = i;
    }
}

// ---------------- zmain: UNMASKED Zall over the upper tile-triangle ----------------
// Zall[i] = sum_{ALL j} exp(D[i,j]). Symmetric D: tile (it, jt=(it+d)&63), d in [0,31]
// (+ d=32 for it<32) covers each unordered tile pair once; each tile scatters
// exp-sums to row-Z and (d>0) col-Z. grid (8 d-groups, 64 i-tiles); 4 waves 2x2;
// A staged via swizzled global_load_lds -> regs; As8 reused as B dbuf slot 1.
__global__ __launch_bounds__(256, 2) void zmain_kernel(const short* __restrict__ embb,
                                                       const float* __restrict__ s2,
                                                       float* __restrict__ Z, int N) {
    __shared__ short8 As8[128 * 16];  // 32 KB: A stage, then B dbuf slot 1
    __shared__ short8 Bs8[128 * 16];  // 32 KB: B dbuf slot 0

    const int tid = threadIdx.x;
    const int w = tid >> 6, l = tid & 63;
    const int wr = w >> 1, wc = w & 1;
    const int g = blockIdx.x, it = blockIdx.y;
    const int i0 = it * 128;
    const short8* embv = (const short8*)embb;

    int dlist[5];
    int nd = 4;
#pragma unroll
    for (int t = 0; t < 4; ++t) dlist[t] = g * 4 + t;
    if (g == 7 && it < 32) dlist[nd++] = 32;

    // stage A tile and first B tile; swizzled source: LDS[row][c] = G[row][c^(row&7)]
#pragma unroll
    for (int itr = 0; itr < 8; ++itr) {
        int lr = w * 32 + itr * 4 + (l >> 4);
        int c = (l & 15) ^ (lr & 7);
        gload_lds16(embv + (size_t)(i0 + lr) * 16 + c, &As8[w * 512 + itr * 64]);
    }
    {
        int j0 = ((it + dlist[0]) & 63) * 128;
#pragma unroll
        for (int itr = 0; itr < 8; ++itr) {
            int lr = w * 32 + itr * 4 + (l >> 4);
            int c = (l & 15) ^ (lr & 7);
            gload_lds16(embv + (size_t)(j0 + lr) * 16 + c, &Bs8[w * 512 + itr * 64]);
        }
    }

    float s2i[4][4];
#pragma unroll
    for (int mi = 0; mi < 4; ++mi)
#pragma unroll
        for (int r = 0; r < 4; ++r)
            s2i[mi][r] = s2[i0 + wr * 64 + mi * 16 + (l >> 4) * 4 + r];
    float zsum[4][4];
#pragma unroll
    for (int mi = 0; mi < 4; ++mi)
#pragma unroll
        for (int r = 0; r < 4; ++r) zsum[mi][r] = 0.f;

    __syncthreads();  // A and B0 staged

    // hoist A fragments (loop-invariant over tiles)
    short8 af[4][4];
#pragma unroll
    for (int mi = 0; mi < 4; ++mi) {
        int row = wr * 64 + mi * 16 + (l & 15);
        int rs = row * 16, rx = row & 7;
#pragma unroll
        for (int ks = 0; ks < 4; ++ks) {
            int kc = ks * 4 + (l >> 4);
            af[mi][ks] = As8[rs + (kc ^ rx)];
        }
    }
    __syncthreads();  // As8 free for B buffering

    for (int t = 0; t < nd; ++t) {
        const int d = dlist[t];
        const int j0 = ((it + d) & 63) * 128;
        short8* rb = (t & 1) ? As8 : Bs8;
        short8* sb = (t & 1) ? Bs8 : As8;
        if (t + 1 < nd) {
            int j1 = ((it + dlist[t + 1]) & 63) * 128;
#pragma unroll
            for (int itr = 0; itr < 8; ++itr) {
                int lr = w * 32 + itr * 4 + (l >> 4);
                int c = (l & 15) ^ (lr & 7);
                gload_lds16(embv + (size_t)(j1 + lr) * 16 + c, &sb[w * 512 + itr * 64]);
            }
        }

        f32x4 acc[4][4];
#pragma unroll
        for (int mi = 0; mi < 4; ++mi)
#pragma unroll
            for (int ni = 0; ni < 4; ++ni) acc[mi][ni] = (f32x4){0.f, 0.f, 0.f, 0.f};

#pragma unroll
        for (int ks = 0; ks < 4; ++ks) {
            short8 bf[4];
            int kc = ks * 4 + (l >> 4);
#pragma unroll
            for (int ni = 0; ni < 4; ++ni) {
                int row = wc * 64 + ni * 16 + (l & 15);
                bf[ni] = rb[row * 16 + (kc ^ (row & 7))];
            }
#pragma unroll
            for (int mi = 0; mi < 4; ++mi)
#pragma unroll
                for (int ni = 0; ni < 4; ++ni)
                    acc[mi][ni] = __builtin_amdgcn_mfma_f32_16x16x32_bf16(af[mi][ks], bf[ni], acc[mi][ni], 0, 0, 0);
        }

        // epilogue: e = 2^(s2i+s2j-2L*dot); row sums always, col sums when d>0
        float s2j[4];
#pragma unroll
        for (int ni = 0; ni < 4; ++ni)
            s2j[ni] = s2[j0 + wc * 64 + ni * 16 + (l & 15)];
        float cs[4] = {0.f, 0.f, 0.f, 0.f};
#pragma unroll
        for (int mi = 0; mi < 4; ++mi)
#pragma unroll
            for (int ni = 0; ni < 4; ++ni)
#pragma unroll
                for (int r = 0; r < 4; ++r) {
                    float e = vexp2(fmaf(NEG2L, acc[mi][ni][r], s2i[mi][r] + s2j[ni]));
                    zsum[mi][r] += e;
                    cs[ni] += e;
                }
        if (d > 0) {
#pragma unroll
            for (int ni = 0; ni < 4; ++ni) {
                float v = cs[ni];
                v += __shfl_xor(v, 16, 64);
                v += __shfl_xor(v, 32, 64);
                if ((l >> 4) == 0)
                    atomicAdd(&Z[j0 + wc * 64 + ni * 16 + (l & 15)], v);
            }
        }
        __syncthreads();  // staged sb landed; all waves done with rb
    }

    // row-side reduce across the 16 lanes sharing each i, atomic into Z
#pragma unroll
    for (int mi = 0; mi < 4; ++mi)
#pragma unroll
        for (int r = 0; r < 4; ++r) {
            float v = zsum[mi][r];
            v += __shfl_xor(v, 1, 64);
            v += __shfl_xor(v, 2, 64);
            v += __shfl_xor(v, 4, 64);
            v += __shfl_xor(v, 8, 64);
            if ((l & 15) == 0)
                atomicAdd(&Z[i0 + wr * 64 + mi * 16 + (l >> 4) * 4 + r], v);
        }
}

// ---------------- Gram quadrant helper for the loss kernel ----------------
__device__ __forceinline__ void gram_quad(const short8* Ms8, int l, int wr, int wc,
                                          int qi, int qj, f32x4 acc[4][4]) {
#pragma unroll
    for (int mi = 0; mi < 4; ++mi)
#pragma unroll
        for (int ni = 0; ni < 4; ++ni) acc[mi][ni] = (f32x4){0.f, 0.f, 0.f, 0.f};
#pragma unroll
    for (int ks = 0; ks < 4; ++ks) {
        short8 af[4], bf[4];
        int kc = ks * 4 + (l >> 4);
#pragma unroll
        for (int mi = 0; mi < 4; ++mi) {
            int row = qi * 128 + wr * 64 + mi * 16 + (l & 15);
            af[mi] = Ms8[row * 16 + (kc ^ (row & 7))];
        }
#pragma unroll
        for (int ni = 0; ni < 4; ++ni) {
            int row = qj * 128 + wc * 64 + ni * 16 + (l & 15);
            bf[ni] = Ms8[row * 16 + (kc ^ (row & 7))];
        }
#pragma unroll
        for (int mi = 0; mi < 4; ++mi)
#pragma unroll
            for (int ni = 0; ni < 4; ++ni)
                acc[mi][ni] = __builtin_amdgcn_mfma_f32_16x16x32_bf16(af[mi], bf[ni], acc[mi][ni], 0, 0, 0);
    }
}

// ---------------- loss: grid (2 halves, 64 labels), fully self-contained ----------------
// Phase 1: same-label Gram quadrants (0,0)[,(0,1),(1,1)] -> zsub row+col exp sums in LDS.
// Zf[pos] = Zall[gid] - zsub[pos] for ALL positions (local => no cross-block anchor dep).
// Phase 2: recompute own-half quadrants -> sum log2(1 + Zf[anchor] * 2^(-D*log2e)).
__global__ __launch_bounds__(256, 2) void loss_kernel(const short* __restrict__ embb,
                                                      const float* __restrict__ s2,
                                                      const float* __restrict__ Z,
                                                      const int* __restrict__ cnt,
                                                      const int* __restrict__ off,
                                                      const int* __restrict__ list,
                                                      float* __restrict__ lsum) {
    __shared__ short8 Ms8[256 * 16];  // 64 KB staged rows
    __shared__ float s2L[256], zfL[256], zsubL[256];
    __shared__ int gidL[256];
    __shared__ float red[4];

    const int h = blockIdx.x, c = blockIdx.y;
    const int k = cnt[c], base = off[c];
    if (k < 2) return;
    const int kp = min(k, 256);
    if (h == 1 && kp <= 128) return;

    const int tid = threadIdx.x;
    const int w = tid >> 6, l = tid & 63;
    const int wr = w >> 1, wc = w & 1;
    const short8* embv = (const short8*)embb;

    {   // metadata
        int pos = tid;
        int gg = list[base + min(pos, k - 1)];
        bool ok = pos < k;
        s2L[pos] = ok ? s2[gg] : 0.f;
        gidL[pos] = ok ? gg : 0x7fffffff;
        zsubL[pos] = 0.f;
    }
    // stage rows (gathered, swizzled): LDS[row][ch] = G[row][ch^(row&7)]
#pragma unroll
    for (int itr = 0; itr < 16; ++itr) {
        int grp = w * 16 + itr;
        if (grp * 4 >= kp) break;  // wave-uniform
        int lr = grp * 4 + (l >> 4);
        int ch = (l & 15) ^ (lr & 7);
        int gg = list[base + min(lr, k - 1)];
        gload_lds16(embv + (size_t)gg * 16 + ch, &Ms8[grp * 64]);
    }
    __syncthreads();

    const int two = (kp > 128);
    f32x4 acc[4][4];

    // ---- phase 1: zsub ----
    for (int qq = 0; qq <= 2 * two; ++qq) {
        int qi = (qq == 2) ? 1 : 0;
        int qj = (qq == 0) ? 0 : 1;
        gram_quad(Ms8, l, wr, wc, qi, qj, acc);
        float rowsum[4][4];
#pragma unroll
        for (int mi = 0; mi < 4; ++mi)
#pragma unroll
            for (int r = 0; r < 4; ++r) rowsum[mi][r] = 0.f;
        float colsum[4] = {0.f, 0.f, 0.f, 0.f};
#pragma unroll
        for (int mi = 0; mi < 4; ++mi)
#pragma unroll
            for (int ni = 0; ni < 4; ++ni) {
                int pB = qi * 128 + wr * 64 + mi * 16 + (l >> 4) * 4;
                int qL = qj * 128 + wc * 64 + ni * 16 + (l & 15);
                float sj = s2L[qL];
#pragma unroll
                for (int r = 0; r < 4; ++r) {
                    float e = vexp2(fmaf(NEG2L, acc[mi][ni][r], s2L[pB + r] + sj));
                    e = ((pB + r) < k && qL < k) ? e : 0.f;
                    rowsum[mi][r] += e;
                    colsum[ni] += e;
                }
            }
#pragma unroll
        for (int mi = 0; mi < 4; ++mi)
#pragma unroll
            for (int r = 0; r < 4; ++r) {
                float v = rowsum[mi][r];
                v += __shfl_xor(v, 1, 64);
                v += __shfl_xor(v, 2, 64);
                v += __shfl_xor(v, 4, 64);
                v += __shfl_xor(v, 8, 64);
                if ((l & 15) == 0)
                    atomicAdd(&zsubL[qi * 128 + wr * 64 + mi * 16 + (l >> 4) * 4 + r], v);
            }
        if (qi != qj) {
#pragma unroll
            for (int ni = 0; ni < 4; ++ni) {
                float v = colsum[ni];
                v += __shfl_xor(v, 16, 64);
                v += __shfl_xor(v, 32, 64);
                if ((l >> 4) == 0)
                    atomicAdd(&zsubL[qj * 128 + wc * 64 + ni * 16 + (l & 15)], v);
            }
        }
    }
    __syncthreads();
    {   // Zf = Zall - zsub, all positions local
        int pos = tid;
        zfL[pos] = (pos < k) ? (Z[gidL[pos]] - zsubL[pos]) : 0.f;
    }
    __syncthreads();

    // ---- phase 2: loss over own-half pairs ----
    float part = 0.f;
    int q0 = (h == 0) ? 0 : 2;                    // h=0: quadrants (0,0),(0,1); h=1: (1,1)
    int q1 = (h == 0) ? (two ? 1 : 0) : 2;
    for (int qq = q0; qq <= q1; ++qq) {
        int qi = (qq == 2) ? 1 : 0;
        int qj = (qq == 0) ? 0 : 1;
        gram_quad(Ms8, l, wr, wc, qi, qj, acc);
#pragma unroll
        for (int mi = 0; mi < 4; ++mi)
#pragma unroll
            for (int ni = 0; ni < 4; ++ni) {
                int qL = qj * 128 + wc * 64 + ni * 16 + (l & 15);
                float sj = s2L[qL];
                float zq = zfL[qL];
                int gb = gidL[qL];
#pragma unroll
                for (int r = 0; r < 4; ++r) {
                    int pL = qi * 128 + wr * 64 + mi * 16 + (l >> 4) * 4 + r;
                    bool valid = (pL < qL) && (qL < k);
                    float arg = fmaf(POS2L, acc[mi][ni][r], -(s2L[pL] + sj));
                    arg = valid ? arg : -160.f;   // 2^-160 -> 0
                    float e = vexp2(arg);
                    float z = (gidL[pL] < gb) ? zfL[pL] : zq;
                    part += vlog2(fmaf(z, e, 1.0f));
                }
            }
    }

    for (int m = 32; m; m >>= 1) part += __shfl_xor(part, m, 64);
    if (l == 0) red[w] = part;
    __syncthreads();
    if (tid == 0)
        atomicAdd(&lsum[c], red[0] + red[1] + red[2] + red[3]);
}

// ---------------- finalize: per-label mean (lsum is in log2 units), mean over valid ----------------
__global__ void fin_kernel(const float* __restrict__ lsum, const int* __restrict__ cnt,
                           float* __restrict__ out) {
    int c = threadIdx.x;
    float mean = 0.f;
    int valid = 0;
    if (c < NCLS) {
        long k = cnt[c];
        long np = k * (k - 1) / 2;
        if (np > 0) { mean = lsum[c] * 0.6931471805599453f / (float)np; valid = 1; }
    }
    float sm = mean;
    int sv = valid;
    for (int m = 32; m; m >>= 1) {
        sm += __shfl_xor(sm, m, 64);
        sv += __shfl_xor(sv, m, 64);
    }
    if (c == 0) out[0] = sm / (float)max(sv, 1);
}

extern "C" void kernel_launch(void* const* d_in, const int* in_sizes, int n_in,
                              void* d_out, int out_size, void* d_ws, size_t ws_size,
                              hipStream_t stream) {
    const float* emb = (const float*)d_in[0];
    const int* lab = (const int*)d_in[1];
    float* out = (float*)d_out;
    const int N = in_sizes[1];  // 8192

    // workspace (4B units): [Z | lsum] zeroed in one memset
    float* ws = (float*)d_ws;
    float* Z = ws;                          // N (Zall)
    float* lsum = ws + N;                   // 64
    int* cnt = (int*)(ws + N + NCLS);       // 64
    int* off = cnt + NCLS;                  // 64
    int* list = off + NCLS;                 // N
    float* s2 = (float*)(list + N);         // N (sq * log2e)
    short* embb = (short*)(s2 + N);         // N*KD bf16 (2 MB), 16B-aligned

    hipMemsetAsync(Z, 0, (size_t)(N + NCLS) * 4, stream);
    scan_scatter_kernel<<<1, 1024, 0, stream>>>(lab, cnt, off, list, N);   // window-resident
    cvtprep_kernel<<<N / 16, 256, 0, stream>>>(emb, embb, s2, N);          // window-resident
    dim3 zgrid(8, N / 128);
    zmain_kernel<<<zgrid, 256, 0, stream>>>(embb, s2, Z, N);
    dim3 lgrid(2, NCLS);
    loss_kernel<<<lgrid, 256, 0, stream>>>(embb, s2, Z, cnt, off, list, lsum);
    fin_kernel<<<1, 64, 0, stream>>>(lsum, cnt, out);
}